// Round 5
// baseline (77.418 us; speedup 1.0000x reference)
//
#include <hip/hip_runtime.h>
#include <hip/hip_bf16.h>
#include <cstdint>

typedef unsigned short u16;
typedef __attribute__((ext_vector_type(8)))  short bf16x8;   // 8 bf16 in 4 VGPR
typedef __attribute__((ext_vector_type(4)))  float f32x4;
typedef __attribute__((ext_vector_type(16))) float f32x16;
typedef __attribute__((ext_vector_type(2)))  unsigned int uint2v;

#define N_TOK   2048
#define DMODEL  1024
#define NHEAD   16
#define DHEAD   64
#define QKV_N   3072
#define QK_LD   2048
#define NSPLIT  4
#define KV_PER  (N_TOK / NSPLIT)
#define C1_LOG2 0.1803368801111244f   // (1/8) * log2(e), folded into Q at GEMM epilogue
#define M0_BASE 4.0f                  // constant softmax base (log2 domain)

// ---------- helpers ----------
__device__ __forceinline__ u16 f2b(float f) {          // f32 -> bf16 bits, RNE
  uint32_t u = __float_as_uint(f);
  u += 0x7FFFu + ((u >> 16) & 1u);
  return (u16)(u >> 16);
}
__device__ __forceinline__ float b2f(u16 b) {
  return __uint_as_float(((uint32_t)b) << 16);
}
__device__ __forceinline__ float fexp2(float x) { return __builtin_amdgcn_exp2f(x); }

__device__ __forceinline__ uint32_t cvtpk(float lo, float hi) {
  uint32_t r;
  asm("v_cvt_pk_bf16_f32 %0, %1, %2" : "=v"(r) : "v"(lo), "v"(hi));
  return r;
}

// cross-half (lane i <-> lane i+32) sum via permlane32_swap
__device__ __forceinline__ float xsum32(float x) {
  uint2v d = __builtin_amdgcn_permlane32_swap(__float_as_uint(x), __float_as_uint(x), false, false);
  return __uint_as_float(d.x) + __uint_as_float(d.y);
}

__device__ __forceinline__ void gload_lds16(const void* g, void* l) {
  __builtin_amdgcn_global_load_lds(
      (const __attribute__((address_space(1))) void*)g,
      (__attribute__((address_space(3))) void*)l,
      16, 0, 0);
}

// ---------- f32 -> bf16 convert, all three tensors in one launch ----------
__global__ __launch_bounds__(256)
void cvt_all(const float* __restrict__ x, const float* __restrict__ wq,
             const float* __restrict__ wp,
             u16* __restrict__ xb, u16* __restrict__ wqb, u16* __restrict__ wpb) {
  const int i = blockIdx.x * 256 + threadIdx.x;           // float4 index
  const int NX = (N_TOK * DMODEL) / 4;                    // 524288
  const int NQ = (3 * DMODEL * DMODEL) / 4;               // 786432
  const float4* src; u16* dst; int j;
  if (i < NX)            { src = (const float4*)x;  dst = xb;  j = i; }
  else if (i < NX + NQ)  { src = (const float4*)wq; dst = wqb; j = i - NX; }
  else                   { src = (const float4*)wp; dst = wpb; j = i - NX - NQ; }
  const float4 v = src[j];
  ushort4 pk;
  pk.x = f2b(v.x); pk.y = f2b(v.y); pk.z = f2b(v.z); pk.w = f2b(v.w);
  ((ushort4*)dst)[j] = pk;
}

// ---------- NT GEMM: C[m][n] = sum_k A[m,k]*B[n,k] + bias[n] ----------
// Tile BM = MI*32, BN = NI*32; 4 waves in 2x2; dbuf LDS; counted-vmcnt schedule.
// A and B both LDS-staged via global_load_lds (known-good R0/R4 structure —
// the A-in-reg variant spilled at the 128-VGPR/2-block cap and regressed 2x;
// 1 block/CU variants regressed: 2 blocks/CU mandatory in this family).
// FUSE_VT: col>=2D writes transposed V to vtg; col<D scales (acc+bias) by C1_LOG2 (Q).
template<bool OUT_F32, bool FUSE_VT, int MI, int NI>
__global__ __launch_bounds__(256, 2)
void gemm_nt(const u16* __restrict__ A, const u16* __restrict__ B,
             const float* __restrict__ bias, void* __restrict__ Cv,
             u16* __restrict__ vtg, int ldc, int K) {
  __shared__ alignas(16) u16 As[2][MI * 32 * 64];
  __shared__ alignas(16) u16 Bs[2][NI * 32 * 64];
  const int tid = threadIdx.x;
  const int w = tid >> 6, l = tid & 63;
  const int lo = l & 15, hi = l >> 4;
  const int wr = w >> 1, wc = w & 1;
  const int bm = blockIdx.y * (MI * 32), bn = blockIdx.x * (NI * 32);
  f32x4 acc[MI][NI] = {};
  const int NK = K >> 6;

  auto stage = [&](int kb, int bufi) {
#pragma unroll
    for (int i = 0; i < MI; ++i) {                       // A: MI*256 chunks of 16B
      const int c = w * (MI * 64) + i * 64 + l;
      const int r = c >> 3, gs = (c ^ r) & 7;
      gload_lds16(A + (size_t)(bm + r) * K + kb + gs * 8, (char*)As[bufi] + (size_t)c * 16);
    }
#pragma unroll
    for (int i = 0; i < NI; ++i) {                       // B: NI*256 chunks
      const int c = w * (NI * 64) + i * 64 + l;
      const int r = c >> 3, gs = (c ^ r) & 7;
      gload_lds16(B + (size_t)(bn + r) * K + kb + gs * 8, (char*)Bs[bufi] + (size_t)c * 16);
    }
  };

  stage(0, 0);
  int buf = 0;
  for (int t = 0; t < NK; ++t) {
    if (t + 1 < NK) {
      stage((t + 1) * 64, buf ^ 1);
      if constexpr (MI + NI == 7)      asm volatile("s_waitcnt vmcnt(7)" ::: "memory");
      else if constexpr (MI + NI == 6) asm volatile("s_waitcnt vmcnt(6)" ::: "memory");
      else if constexpr (MI + NI == 4) asm volatile("s_waitcnt vmcnt(4)" ::: "memory");
      else                             asm volatile("s_waitcnt vmcnt(8)" ::: "memory");
    } else {
      asm volatile("s_waitcnt vmcnt(0)" ::: "memory");
    }
    __builtin_amdgcn_s_barrier();                        // all waves: buf ready

    bf16x8 af[MI][2], bfr[NI][2];
#pragma unroll
    for (int mi = 0; mi < MI; ++mi)
#pragma unroll
      for (int ks = 0; ks < 2; ++ks) {
        const int ra = wr * (MI * 16) + mi * 16 + lo;
        af[mi][ks] = *(const bf16x8*)((const char*)As[buf] + ra * 128 +
                                      (((ks * 4 + hi) ^ (ra & 7)) << 4));
      }
#pragma unroll
    for (int ni = 0; ni < NI; ++ni)
#pragma unroll
      for (int ks = 0; ks < 2; ++ks) {
        const int rb = wc * (NI * 16) + ni * 16 + lo;
        bfr[ni][ks] = *(const bf16x8*)((const char*)Bs[buf] + rb * 128 +
                                       (((ks * 4 + hi) ^ (rb & 7)) << 4));
      }
#pragma unroll
    for (int mi = 0; mi < MI; ++mi)
#pragma unroll
      for (int ni = 0; ni < NI; ++ni)
#pragma unroll
        for (int ks = 0; ks < 2; ++ks)
          acc[mi][ni] = __builtin_amdgcn_mfma_f32_16x16x32_bf16(af[mi][ks], bfr[ni][ks], acc[mi][ni], 0, 0, 0);

    __builtin_amdgcn_s_barrier();                        // all waves done reading buf
    buf ^= 1;
  }

#pragma unroll
  for (int mi = 0; mi < MI; ++mi)
#pragma unroll
    for (int ni = 0; ni < NI; ++ni) {
      const int col = bn + wc * (NI * 16) + ni * 16 + lo;
      const float bv = bias[col];
      if constexpr (FUSE_VT) {
        if (col >= 2 * DMODEL) {
          // transposed V write: vtg[(col-2D)*N_TOK + row], 4 consecutive rows
          const int row0 = bm + wr * (MI * 16) + mi * 16 + hi * 4;
          ushort4 pk;
          pk.x = f2b(acc[mi][ni][0] + bv);
          pk.y = f2b(acc[mi][ni][1] + bv);
          pk.z = f2b(acc[mi][ni][2] + bv);
          pk.w = f2b(acc[mi][ni][3] + bv);
          *(ushort4*)(vtg + (size_t)(col - 2 * DMODEL) * N_TOK + row0) = pk;
        } else {
          const float sc = (col < DMODEL) ? C1_LOG2 : 1.0f;   // fold softmax scale into Q
#pragma unroll
          for (int j = 0; j < 4; ++j) {
            const int row = bm + wr * (MI * 16) + mi * 16 + hi * 4 + j;
            ((u16*)Cv)[(size_t)row * QK_LD + col] = f2b((acc[mi][ni][j] + bv) * sc);
          }
        }
      } else {
#pragma unroll
        for (int j = 0; j < 4; ++j) {
          const int row = bm + wr * (MI * 16) + mi * 16 + hi * 4 + j;
          const float v = acc[mi][ni][j] + bv;
          if constexpr (OUT_F32) ((float*)Cv)[(size_t)row * ldc + col] = v;
          else                   ((u16*)Cv)[(size_t)row * ldc + col] = f2b(v);
        }
      }
    }
}

// ---------- flash attention partial, constant-base softmax (no max tracking) ----------
// grid: 512 blocks = 8 qb x 16 h x 4 z (XCD-swizzled), 256 thr = 4 waves, 2 blocks/CU.
// 64 q-rows per wave (two 32-q groups share every K/V fragment read).
// R5: PV split by q-group with V-frags register-cached; SOFTPACK(group1) issues
// between PV0 and PV1 so its VALU overlaps PV0's MFMA drain (separate pipes).
#define FRAG(BASE, ROW, SLOT) \
  (*(const bf16x8*)((const char*)(BASE) + (ROW) * 128 + ((((SLOT) ^ ((ROW) & 7))) << 4)))

// strip-wise exp2 -> sum -> pack (T12); P = 2^(s - M0)
#define SOFTPACK(SA, SB, PFR, LS) do {                                          \
    float tsum_ = 0.f;                                                          \
    _Pragma("unroll")                                                           \
    for (int ks = 0; ks < 4; ++ks) {                                            \
      float q_[8];                                                              \
      _Pragma("unroll")                                                         \
      for (int j = 0; j < 8; ++j) {                                             \
        const int idx = (ks & 1) * 8 + j;                                       \
        q_[j] = fexp2(((ks < 2) ? (SA)[idx] : (SB)[idx]) - M0_BASE);            \
      }                                                                         \
      tsum_ += ((q_[0] + q_[1]) + (q_[2] + q_[3])) + ((q_[4] + q_[5]) + (q_[6] + q_[7])); \
      uint32_t a1 = cvtpk(q_[0], q_[1]);                                        \
      uint32_t a2 = cvtpk(q_[2], q_[3]);                                        \
      uint32_t b1 = cvtpk(q_[4], q_[5]);                                        \
      uint32_t b2 = cvtpk(q_[6], q_[7]);                                        \
      uint2v r1 = __builtin_amdgcn_permlane32_swap(a1, b1, false, false);       \
      uint2v r2 = __builtin_amdgcn_permlane32_swap(a2, b2, false, false);       \
      union { uint32_t u[4]; bf16x8 h; } cv_;                                   \
      cv_.u[0] = r1.x; cv_.u[1] = r2.x; cv_.u[2] = r1.y; cv_.u[3] = r2.y;       \
      (PFR)[ks] = cv_.h;                                                        \
    }                                                                           \
    (LS) += tsum_;                                                              \
  } while (0)

__global__ __launch_bounds__(256, 2)
void attn3(const u16* __restrict__ qkb, const u16* __restrict__ vtg,
           u16* __restrict__ PO, float* __restrict__ lbuf) {
  // unified LDS: K dbuf = SMEM[0..1], V dbuf = SMEM[2..3]; epilogue reuses all 32KB
  __shared__ alignas(16) u16 SMEM[4][64 * 64];
  const int tid = threadIdx.x;
  const int w = tid >> 6, l = tid & 63;
  const int lo = l & 31, hi = l >> 5;

  int bid = (int)blockIdx.x;
  bid = (bid & 7) * 64 + (bid >> 3);          // XCD swizzle (512 % 8 == 0, bijective)
  const int h  = bid >> 5;                    // 2 heads per XCD chunk -> K/V L2-resident
  const int qb = (bid >> 2) & 7;
  const int z  = bid & 3;
  const int q0w = qb * 256 + w * 64;          // wave's 64 q-rows
  const int kv0 = z * KV_PER;

  // Q fragments (B-operand of swapped QK), two 32-q groups:
  // lane holds Qs[q0w + qg*32 + lo][ds*16 + hi*8 + j]
  bf16x8 qf0[4], qf1[4];
  {
    const u16* qs0 = qkb + (size_t)(q0w + lo) * QK_LD + h * 64 + hi * 8;
    const u16* qs1 = qkb + (size_t)(q0w + 32 + lo) * QK_LD + h * 64 + hi * 8;
#pragma unroll
    for (int ds = 0; ds < 4; ++ds) { qf0[ds] = *(const bf16x8*)(qs0 + ds * 16);
                                     qf1[ds] = *(const bf16x8*)(qs1 + ds * 16); }
  }

  f32x16 o0 = {}, o1 = {}, o2 = {}, o3 = {};
  float lsum0 = 0.f, lsum1 = 0.f;

#define STAGE(KB, B) do {                                                       \
    _Pragma("unroll")                                                           \
    for (int i_ = 0; i_ < 2; ++i_) {                                            \
      const int c_ = w * 128 + i_ * 64 + l;                                     \
      const int r_ = c_ >> 3;                                                   \
      const int gs_ = (c_ ^ r_) & 7;                                            \
      gload_lds16(qkb + (size_t)((KB) + r_) * QK_LD + DMODEL + h * 64 + gs_ * 8,\
                  (char*)SMEM[B] + (size_t)(w * 128 + i_ * 64) * 16);           \
      gload_lds16(vtg + (size_t)(h * 64 + r_) * N_TOK + (KB) + gs_ * 8,         \
                  (char*)SMEM[2 + (B)] + (size_t)(w * 128 + i_ * 64) * 16);     \
    }                                                                           \
  } while (0)

  STAGE(kv0, 0);
  int buf = 0;
  for (int t = 0; t < KV_PER / 64; ++t) {
    if (t + 1 < KV_PER / 64) {
      STAGE(kv0 + (t + 1) * 64, buf ^ 1);
      asm volatile("s_waitcnt vmcnt(4)" ::: "memory");   // stage(t) landed (own 4 ops)
    } else {
      asm volatile("s_waitcnt vmcnt(0)" ::: "memory");
    }
    __builtin_amdgcn_s_barrier();                        // all waves: buf ready

    const u16* Kb = SMEM[buf];
    const u16* Vb = SMEM[2 + buf];

    // S^T(log2-domain) = Kb . Qs^T  (rows kv, cols q); K-frags shared by both q-groups
    f32x16 s0 = {}, s1 = {}, s2 = {}, s3 = {};
    __builtin_amdgcn_s_setprio(1);
#pragma unroll
    for (int ds = 0; ds < 4; ++ds) {
      bf16x8 k0 = FRAG(Kb, lo, ds * 2 + hi);
      bf16x8 k1 = FRAG(Kb, 32 + lo, ds * 2 + hi);
      s0 = __builtin_amdgcn_mfma_f32_32x32x16_bf16(k0, qf0[ds], s0, 0, 0, 0);
      s1 = __builtin_amdgcn_mfma_f32_32x32x16_bf16(k1, qf0[ds], s1, 0, 0, 0);
      s2 = __builtin_amdgcn_mfma_f32_32x32x16_bf16(k0, qf1[ds], s2, 0, 0, 0);
      s3 = __builtin_amdgcn_mfma_f32_32x32x16_bf16(k1, qf1[ds], s3, 0, 0, 0);
    }
    __builtin_amdgcn_s_setprio(0);

    bf16x8 pfr0[4], pfr1[4];
    SOFTPACK(s0, s1, pfr0, lsum0);

    // PV group 0; V-frags cached in regs (8 ds_reads total, reused by group 1)
    bf16x8 vf0[4], vf1[4];
    __builtin_amdgcn_s_setprio(1);
#pragma unroll
    for (int ks = 0; ks < 4; ++ks) {
      vf0[ks] = FRAG(Vb, lo, ks * 2 + hi);
      vf1[ks] = FRAG(Vb, 32 + lo, ks * 2 + hi);
      o0 = __builtin_amdgcn_mfma_f32_32x32x16_bf16(vf0[ks], pfr0[ks], o0, 0, 0, 0);
      o1 = __builtin_amdgcn_mfma_f32_32x32x16_bf16(vf1[ks], pfr0[ks], o1, 0, 0, 0);
    }
    __builtin_amdgcn_s_setprio(0);

    // group-1 softmax VALU overlaps PV0's MFMA drain (separate pipes, same wave)
    SOFTPACK(s2, s3, pfr1, lsum1);

    __builtin_amdgcn_s_setprio(1);
#pragma unroll
    for (int ks = 0; ks < 4; ++ks) {
      o2 = __builtin_amdgcn_mfma_f32_32x32x16_bf16(vf0[ks], pfr1[ks], o2, 0, 0, 0);
      o3 = __builtin_amdgcn_mfma_f32_32x32x16_bf16(vf1[ks], pfr1[ks], o3, 0, 0, 0);
    }
    __builtin_amdgcn_s_setprio(0);

    __builtin_amdgcn_s_barrier();                        // all waves done reading buf
    buf ^= 1;
  }
#undef STAGE

  lsum0 = xsum32(lsum0);                                 // full row sums (one swap each)
  lsum1 = xsum32(lsum1);

  // epilogue: normalized partial O/l -> LDS transpose (wave-private 64x64) -> PO bf16
  u16* Ow = ((u16*)SMEM) + w * 4096;            // 64 rows x 64 cols per wave
  const float inv0 = 1.0f / lsum0;
  const float inv1 = 1.0f / lsum1;
#pragma unroll
  for (int r = 0; r < 16; ++r) {
    const int crow = (r & 3) + 8 * (r >> 2) + 4 * hi;
    const int c0 = crow, c1 = 32 + crow;
    const int s0i = ((c0 >> 3) ^ (lo & 7)) << 3, s1i = ((c1 >> 3) ^ (lo & 7)) << 3;
    Ow[lo * 64 + s0i + (c0 & 7)] = f2b(o0[r] * inv0);
    Ow[lo * 64 + s1i + (c1 & 7)] = f2b(o1[r] * inv0);
    Ow[(32 + lo) * 64 + s0i + (c0 & 7)] = f2b(o2[r] * inv1);   // (32+lo)&7 == lo&7
    Ow[(32 + lo) * 64 + s1i + (c1 & 7)] = f2b(o3[r] * inv1);
  }
  if (hi == 0) {
    lbuf[((size_t)z * NHEAD + h) * N_TOK + q0w + lo] = lsum0;
    lbuf[((size_t)z * NHEAD + h) * N_TOK + q0w + 32 + lo] = lsum1;
  }
  asm volatile("s_waitcnt lgkmcnt(0)" ::: "memory");
  __builtin_amdgcn_sched_barrier(0);
  u16* pobase = PO + (((size_t)z * NHEAD + h) * N_TOK + q0w) * DHEAD;
#pragma unroll
  for (int i = 0; i < 8; ++i) {
    const int c = i * 64 + l;
    const int rr = c >> 3, sl = c & 7;
    bf16x8 v = *(const bf16x8*)(Ow + rr * 64 + sl * 8);
    const int cs = sl ^ (rr & 7);
    *(bf16x8*)(pobase + (size_t)rr * DHEAD + cs * 8) = v;
  }
}

// ---------- combine 4 partials: same base everywhere -> weights are just l_z ----------
__global__ __launch_bounds__(256)
void combine(const u16* __restrict__ PO, const float* __restrict__ lbuf,
             u16* __restrict__ attb) {
  const int idx = blockIdx.x * 256 + threadIdx.x;        // 0 .. 256*1024-1
  const int row = idx >> 3;                              // 0 .. N_TOK*NHEAD-1
  const int c8  = (idx & 7) * 8;
  const int h = row >> 11;
  const int q = row & (N_TOK - 1);

  float wsum = 0.f, acc8[8] = {};
#pragma unroll
  for (int zz = 0; zz < NSPLIT; ++zz) {
    const float wz = lbuf[((size_t)zz * NHEAD + h) * N_TOK + q];
    wsum += wz;
    bf16x8 po = *(const bf16x8*)(PO + (((size_t)zz * NHEAD + h) * N_TOK + q) * DHEAD + c8);
#pragma unroll
    for (int j = 0; j < 8; ++j) acc8[j] += wz * b2f((u16)po[j]);
  }
  const float invw = 1.0f / wsum;
  union { u16 s[8]; bf16x8 h8; } ov;
#pragma unroll
  for (int j = 0; j < 8; ++j) ov.s[j] = f2b(acc8[j] * invw);
  *(bf16x8*)(attb + (size_t)q * DMODEL + h * 64 + c8) = ov.h8;
}

// ---------- launch ----------
extern "C" void kernel_launch(void* const* d_in, const int* in_sizes, int n_in,
                              void* d_out, int out_size, void* d_ws, size_t ws_size,
                              hipStream_t stream) {
  const float* x      = (const float*)d_in[0];
  const float* w_qkv  = (const float*)d_in[1];
  const float* b_qkv  = (const float*)d_in[2];
  const float* w_proj = (const float*)d_in[3];
  const float* b_proj = (const float*)d_in[4];
  float* out = (float*)d_out;

  char* ws = (char*)d_ws;                          // flat layout, no aliasing
  u16*    xb     = (u16*)(ws + (0u  << 20));       //  4 MB
  u16*    wqkvb  = (u16*)(ws + (8u  << 20));       //  6 MB
  u16*    wprojb = (u16*)(ws + (16u << 20));       //  2 MB
  u16*    qkb    = (u16*)(ws + (24u << 20));       //  8 MB  (N x 2D: Q-scaled | K)
  u16*    vtg    = (u16*)(ws + (40u << 20));       //  4 MB  (H,DH,N)
  u16*    PO     = (u16*)(ws + (48u << 20));       // 16 MB  (4 splits)
  float*  lbuf   = (float*)(ws + (64u << 20));     //  0.5 MB
  u16*    attb   = (u16*)(ws + (66u << 20));       //  4 MB
  if (ws_size < (80u << 20)) return;

  cvt_all<<<6144, 256, 0, stream>>>(x, w_qkv, w_proj, xb, wqkvb, wprojb);

  // QKV GEMM, BM=128/BN=96 (MI=4,NI=3): 512 blocks = 2/CU, LDS-both (known-good).
  gemm_nt<false, true, 4, 3><<<dim3(QKV_N / 96, N_TOK / 128), 256, 0, stream>>>(
      xb, wqkvb, b_qkv, (void*)qkb, vtg, QK_LD, DMODEL);

  // 64 q/wave: 8 qb x 16 h x 4 z = 512 blocks = 2/CU, K/V frags reused across 2 q-groups
  attn3<<<8 * NHEAD * NSPLIT, 256, 0, stream>>>(qkb, vtg, PO, lbuf);

  combine<<<(N_TOK * NHEAD * 8) / 256, 256, 0, stream>>>(PO, lbuf, attb);

  // proj GEMM, BM=64/BN=64 (MI=2,NI=2): 512 blocks = 2/CU, LDS-both (R0/R4 config).
  gemm_nt<true, false, 2, 2><<<dim3(DMODEL / 64, N_TOK / 64), 256, 0, stream>>>(
      attb, wprojb, b_proj, (void*)out, nullptr, DMODEL, DMODEL);
}

// Round 6
// 73.000 us; speedup vs baseline: 1.0605x; 1.0605x over previous
//
#include <hip/hip_runtime.h>
#include <hip/hip_bf16.h>
#include <cstdint>

typedef unsigned short u16;
typedef __attribute__((ext_vector_type(8)))  short bf16x8;   // 8 bf16 in 4 VGPR
typedef __attribute__((ext_vector_type(4)))  float f32x4;
typedef __attribute__((ext_vector_type(16))) float f32x16;
typedef __attribute__((ext_vector_type(2)))  unsigned int uint2v;

#define N_TOK   2048
#define DMODEL  1024
#define NHEAD   16
#define DHEAD   64
#define QKV_N   3072
#define QK_LD   2048
#define NSPLIT  4
#define KV_PER  (N_TOK / NSPLIT)
#define C1_LOG2 0.1803368801111244f   // (1/8) * log2(e), folded into Q at GEMM epilogue
#define M0_BASE 4.0f                  // constant softmax base (log2 domain)

// ---------- helpers ----------
__device__ __forceinline__ u16 f2b(float f) {          // f32 -> bf16 bits, RNE
  uint32_t u = __float_as_uint(f);
  u += 0x7FFFu + ((u >> 16) & 1u);
  return (u16)(u >> 16);
}
__device__ __forceinline__ float b2f(u16 b) {
  return __uint_as_float(((uint32_t)b) << 16);
}
__device__ __forceinline__ float fexp2(float x) { return __builtin_amdgcn_exp2f(x); }

__device__ __forceinline__ uint32_t cvtpk(float lo, float hi) {
  uint32_t r;
  asm("v_cvt_pk_bf16_f32 %0, %1, %2" : "=v"(r) : "v"(lo), "v"(hi));
  return r;
}

// cross-half (lane i <-> lane i+32) sum via permlane32_swap
__device__ __forceinline__ float xsum32(float x) {
  uint2v d = __builtin_amdgcn_permlane32_swap(__float_as_uint(x), __float_as_uint(x), false, false);
  return __uint_as_float(d.x) + __uint_as_float(d.y);
}

__device__ __forceinline__ void gload_lds16(const void* g, void* l) {
  __builtin_amdgcn_global_load_lds(
      (const __attribute__((address_space(1))) void*)g,
      (__attribute__((address_space(3))) void*)l,
      16, 0, 0);
}

// ---------- f32 -> bf16 convert, all three tensors in one launch ----------
__global__ __launch_bounds__(256)
void cvt_all(const float* __restrict__ x, const float* __restrict__ wq,
             const float* __restrict__ wp,
             u16* __restrict__ xb, u16* __restrict__ wqb, u16* __restrict__ wpb) {
  const int i = blockIdx.x * 256 + threadIdx.x;           // float4 index
  const int NX = (N_TOK * DMODEL) / 4;                    // 524288
  const int NQ = (3 * DMODEL * DMODEL) / 4;               // 786432
  const float4* src; u16* dst; int j;
  if (i < NX)            { src = (const float4*)x;  dst = xb;  j = i; }
  else if (i < NX + NQ)  { src = (const float4*)wq; dst = wqb; j = i - NX; }
  else                   { src = (const float4*)wp; dst = wpb; j = i - NX - NQ; }
  const float4 v = src[j];
  ushort4 pk;
  pk.x = f2b(v.x); pk.y = f2b(v.y); pk.z = f2b(v.z); pk.w = f2b(v.w);
  ((ushort4*)dst)[j] = pk;
}

// ---------- NT GEMM: C[m][n] = sum_k A[m,k]*B[n,k] + bias[n] ----------
// Tile BM = MI*32, BN = NI*32; 4 waves in 2x2; dbuf LDS; counted-vmcnt schedule.
// A and B both LDS-staged via global_load_lds. Known-good R4 structure:
//  - 2 blocks/CU mandatory (1 blk/CU variants regressed: R2)
//  - no register tiling beyond the 128-VGPR/2-block cap (spilled: R3)
// FUSE_VT: col>=2D writes transposed V to vtg; col<D scales (acc+bias) by C1_LOG2 (Q).
template<bool OUT_F32, bool FUSE_VT, int MI, int NI>
__global__ __launch_bounds__(256, 2)
void gemm_nt(const u16* __restrict__ A, const u16* __restrict__ B,
             const float* __restrict__ bias, void* __restrict__ Cv,
             u16* __restrict__ vtg, int ldc, int K) {
  __shared__ alignas(16) u16 As[2][MI * 32 * 64];
  __shared__ alignas(16) u16 Bs[2][NI * 32 * 64];
  const int tid = threadIdx.x;
  const int w = tid >> 6, l = tid & 63;
  const int lo = l & 15, hi = l >> 4;
  const int wr = w >> 1, wc = w & 1;
  const int bm = blockIdx.y * (MI * 32), bn = blockIdx.x * (NI * 32);
  f32x4 acc[MI][NI] = {};
  const int NK = K >> 6;

  auto stage = [&](int kb, int bufi) {
#pragma unroll
    for (int i = 0; i < MI; ++i) {                       // A: MI*256 chunks of 16B
      const int c = w * (MI * 64) + i * 64 + l;
      const int r = c >> 3, gs = (c ^ r) & 7;
      gload_lds16(A + (size_t)(bm + r) * K + kb + gs * 8, (char*)As[bufi] + (size_t)c * 16);
    }
#pragma unroll
    for (int i = 0; i < NI; ++i) {                       // B: NI*256 chunks
      const int c = w * (NI * 64) + i * 64 + l;
      const int r = c >> 3, gs = (c ^ r) & 7;
      gload_lds16(B + (size_t)(bn + r) * K + kb + gs * 8, (char*)Bs[bufi] + (size_t)c * 16);
    }
  };

  stage(0, 0);
  int buf = 0;
  for (int t = 0; t < NK; ++t) {
    if (t + 1 < NK) {
      stage((t + 1) * 64, buf ^ 1);
      if constexpr (MI + NI == 7)      asm volatile("s_waitcnt vmcnt(7)" ::: "memory");
      else if constexpr (MI + NI == 6) asm volatile("s_waitcnt vmcnt(6)" ::: "memory");
      else if constexpr (MI + NI == 4) asm volatile("s_waitcnt vmcnt(4)" ::: "memory");
      else                             asm volatile("s_waitcnt vmcnt(8)" ::: "memory");
    } else {
      asm volatile("s_waitcnt vmcnt(0)" ::: "memory");
    }
    __builtin_amdgcn_s_barrier();                        // all waves: buf ready

    bf16x8 af[MI][2], bfr[NI][2];
#pragma unroll
    for (int mi = 0; mi < MI; ++mi)
#pragma unroll
      for (int ks = 0; ks < 2; ++ks) {
        const int ra = wr * (MI * 16) + mi * 16 + lo;
        af[mi][ks] = *(const bf16x8*)((const char*)As[buf] + ra * 128 +
                                      (((ks * 4 + hi) ^ (ra & 7)) << 4));
      }
#pragma unroll
    for (int ni = 0; ni < NI; ++ni)
#pragma unroll
      for (int ks = 0; ks < 2; ++ks) {
        const int rb = wc * (NI * 16) + ni * 16 + lo;
        bfr[ni][ks] = *(const bf16x8*)((const char*)Bs[buf] + rb * 128 +
                                       (((ks * 4 + hi) ^ (rb & 7)) << 4));
      }
#pragma unroll
    for (int mi = 0; mi < MI; ++mi)
#pragma unroll
      for (int ni = 0; ni < NI; ++ni)
#pragma unroll
        for (int ks = 0; ks < 2; ++ks)
          acc[mi][ni] = __builtin_amdgcn_mfma_f32_16x16x32_bf16(af[mi][ks], bfr[ni][ks], acc[mi][ni], 0, 0, 0);

    __builtin_amdgcn_s_barrier();                        // all waves done reading buf
    buf ^= 1;
  }

#pragma unroll
  for (int mi = 0; mi < MI; ++mi)
#pragma unroll
    for (int ni = 0; ni < NI; ++ni) {
      const int col = bn + wc * (NI * 16) + ni * 16 + lo;
      const float bv = bias[col];
      if constexpr (FUSE_VT) {
        if (col >= 2 * DMODEL) {
          // transposed V write: vtg[(col-2D)*N_TOK + row], 4 consecutive rows
          const int row0 = bm + wr * (MI * 16) + mi * 16 + hi * 4;
          ushort4 pk;
          pk.x = f2b(acc[mi][ni][0] + bv);
          pk.y = f2b(acc[mi][ni][1] + bv);
          pk.z = f2b(acc[mi][ni][2] + bv);
          pk.w = f2b(acc[mi][ni][3] + bv);
          *(ushort4*)(vtg + (size_t)(col - 2 * DMODEL) * N_TOK + row0) = pk;
        } else {
          const float sc = (col < DMODEL) ? C1_LOG2 : 1.0f;   // fold softmax scale into Q
#pragma unroll
          for (int j = 0; j < 4; ++j) {
            const int row = bm + wr * (MI * 16) + mi * 16 + hi * 4 + j;
            ((u16*)Cv)[(size_t)row * QK_LD + col] = f2b((acc[mi][ni][j] + bv) * sc);
          }
        }
      } else {
#pragma unroll
        for (int j = 0; j < 4; ++j) {
          const int row = bm + wr * (MI * 16) + mi * 16 + hi * 4 + j;
          const float v = acc[mi][ni][j] + bv;
          if constexpr (OUT_F32) ((float*)Cv)[(size_t)row * ldc + col] = v;
          else                   ((u16*)Cv)[(size_t)row * ldc + col] = f2b(v);
        }
      }
    }
}

// ---------- flash attention partial, constant-base softmax (no max tracking) ----------
// grid: 512 blocks = 8 qb x 16 h x 4 z (XCD-swizzled), 256 thr = 4 waves, 2 blocks/CU.
// 64 q-rows per wave (two 32-q groups share every K/V fragment read: 16 ds_read_b128
// feed 32 MFMA per tile). R4 exact structure — R5's V-frag register cache pushed
// past the VGPR ceiling and regressed; do not add live state here.
#define FRAG(BASE, ROW, SLOT) \
  (*(const bf16x8*)((const char*)(BASE) + (ROW) * 128 + ((((SLOT) ^ ((ROW) & 7))) << 4)))

// strip-wise exp2 -> sum -> pack (T12); P = 2^(s - M0)
#define SOFTPACK(SA, SB, PFR, LS) do {                                          \
    float tsum_ = 0.f;                                                          \
    _Pragma("unroll")                                                           \
    for (int ks = 0; ks < 4; ++ks) {                                            \
      float q_[8];                                                              \
      _Pragma("unroll")                                                         \
      for (int j = 0; j < 8; ++j) {                                             \
        const int idx = (ks & 1) * 8 + j;                                       \
        q_[j] = fexp2(((ks < 2) ? (SA)[idx] : (SB)[idx]) - M0_BASE);            \
      }                                                                         \
      tsum_ += ((q_[0] + q_[1]) + (q_[2] + q_[3])) + ((q_[4] + q_[5]) + (q_[6] + q_[7])); \
      uint32_t a1 = cvtpk(q_[0], q_[1]);                                        \
      uint32_t a2 = cvtpk(q_[2], q_[3]);                                        \
      uint32_t b1 = cvtpk(q_[4], q_[5]);                                        \
      uint32_t b2 = cvtpk(q_[6], q_[7]);                                        \
      uint2v r1 = __builtin_amdgcn_permlane32_swap(a1, b1, false, false);       \
      uint2v r2 = __builtin_amdgcn_permlane32_swap(a2, b2, false, false);       \
      union { uint32_t u[4]; bf16x8 h; } cv_;                                   \
      cv_.u[0] = r1.x; cv_.u[1] = r2.x; cv_.u[2] = r1.y; cv_.u[3] = r2.y;       \
      (PFR)[ks] = cv_.h;                                                        \
    }                                                                           \
    (LS) += tsum_;                                                              \
  } while (0)

__global__ __launch_bounds__(256, 2)
void attn3(const u16* __restrict__ qkb, const u16* __restrict__ vtg,
           u16* __restrict__ PO, float* __restrict__ lbuf) {
  // unified LDS: K dbuf = SMEM[0..1], V dbuf = SMEM[2..3]; epilogue reuses all 32KB
  __shared__ alignas(16) u16 SMEM[4][64 * 64];
  const int tid = threadIdx.x;
  const int w = tid >> 6, l = tid & 63;
  const int lo = l & 31, hi = l >> 5;

  int bid = (int)blockIdx.x;
  bid = (bid & 7) * 64 + (bid >> 3);          // XCD swizzle (512 % 8 == 0, bijective)
  const int h  = bid >> 5;                    // 2 heads per XCD chunk -> K/V L2-resident
  const int qb = (bid >> 2) & 7;
  const int z  = bid & 3;
  const int q0w = qb * 256 + w * 64;          // wave's 64 q-rows
  const int kv0 = z * KV_PER;

  // Q fragments (B-operand of swapped QK), two 32-q groups:
  // lane holds Qs[q0w + qg*32 + lo][ds*16 + hi*8 + j]
  bf16x8 qf0[4], qf1[4];
  {
    const u16* qs0 = qkb + (size_t)(q0w + lo) * QK_LD + h * 64 + hi * 8;
    const u16* qs1 = qkb + (size_t)(q0w + 32 + lo) * QK_LD + h * 64 + hi * 8;
#pragma unroll
    for (int ds = 0; ds < 4; ++ds) { qf0[ds] = *(const bf16x8*)(qs0 + ds * 16);
                                     qf1[ds] = *(const bf16x8*)(qs1 + ds * 16); }
  }

  f32x16 o0 = {}, o1 = {}, o2 = {}, o3 = {};
  float lsum0 = 0.f, lsum1 = 0.f;

#define STAGE(KB, B) do {                                                       \
    _Pragma("unroll")                                                           \
    for (int i_ = 0; i_ < 2; ++i_) {                                            \
      const int c_ = w * 128 + i_ * 64 + l;                                     \
      const int r_ = c_ >> 3;                                                   \
      const int gs_ = (c_ ^ r_) & 7;                                            \
      gload_lds16(qkb + (size_t)((KB) + r_) * QK_LD + DMODEL + h * 64 + gs_ * 8,\
                  (char*)SMEM[B] + (size_t)(w * 128 + i_ * 64) * 16);           \
      gload_lds16(vtg + (size_t)(h * 64 + r_) * N_TOK + (KB) + gs_ * 8,         \
                  (char*)SMEM[2 + (B)] + (size_t)(w * 128 + i_ * 64) * 16);     \
    }                                                                           \
  } while (0)

  STAGE(kv0, 0);
  int buf = 0;
  for (int t = 0; t < KV_PER / 64; ++t) {
    if (t + 1 < KV_PER / 64) {
      STAGE(kv0 + (t + 1) * 64, buf ^ 1);
      asm volatile("s_waitcnt vmcnt(4)" ::: "memory");   // stage(t) landed (own 4 ops)
    } else {
      asm volatile("s_waitcnt vmcnt(0)" ::: "memory");
    }
    __builtin_amdgcn_s_barrier();                        // all waves: buf ready

    const u16* Kb = SMEM[buf];
    const u16* Vb = SMEM[2 + buf];

    // S^T(log2-domain) = Kb . Qs^T  (rows kv, cols q); K-frags shared by both q-groups
    f32x16 s0 = {}, s1 = {}, s2 = {}, s3 = {};
    __builtin_amdgcn_s_setprio(1);
#pragma unroll
    for (int ds = 0; ds < 4; ++ds) {
      bf16x8 k0 = FRAG(Kb, lo, ds * 2 + hi);
      bf16x8 k1 = FRAG(Kb, 32 + lo, ds * 2 + hi);
      s0 = __builtin_amdgcn_mfma_f32_32x32x16_bf16(k0, qf0[ds], s0, 0, 0, 0);
      s1 = __builtin_amdgcn_mfma_f32_32x32x16_bf16(k1, qf0[ds], s1, 0, 0, 0);
      s2 = __builtin_amdgcn_mfma_f32_32x32x16_bf16(k0, qf1[ds], s2, 0, 0, 0);
      s3 = __builtin_amdgcn_mfma_f32_32x32x16_bf16(k1, qf1[ds], s3, 0, 0, 0);
    }
    __builtin_amdgcn_s_setprio(0);

    bf16x8 pfr0[4], pfr1[4];
    SOFTPACK(s0, s1, pfr0, lsum0);
    SOFTPACK(s2, s3, pfr1, lsum1);

    // O^T += V^T . P^T; V-frags shared by both q-groups
    __builtin_amdgcn_s_setprio(1);
#pragma unroll
    for (int ks = 0; ks < 4; ++ks) {
      bf16x8 v0 = FRAG(Vb, lo, ks * 2 + hi);
      bf16x8 v1 = FRAG(Vb, 32 + lo, ks * 2 + hi);
      o0 = __builtin_amdgcn_mfma_f32_32x32x16_bf16(v0, pfr0[ks], o0, 0, 0, 0);
      o1 = __builtin_amdgcn_mfma_f32_32x32x16_bf16(v1, pfr0[ks], o1, 0, 0, 0);
      o2 = __builtin_amdgcn_mfma_f32_32x32x16_bf16(v0, pfr1[ks], o2, 0, 0, 0);
      o3 = __builtin_amdgcn_mfma_f32_32x32x16_bf16(v1, pfr1[ks], o3, 0, 0, 0);
    }
    __builtin_amdgcn_s_setprio(0);

    __builtin_amdgcn_s_barrier();                        // all waves done reading buf
    buf ^= 1;
  }
#undef STAGE

  lsum0 = xsum32(lsum0);                                 // full row sums (one swap each)
  lsum1 = xsum32(lsum1);

  // epilogue: normalized partial O/l -> LDS transpose (wave-private 64x64) -> PO bf16
  u16* Ow = ((u16*)SMEM) + w * 4096;            // 64 rows x 64 cols per wave
  const float inv0 = 1.0f / lsum0;
  const float inv1 = 1.0f / lsum1;
#pragma unroll
  for (int r = 0; r < 16; ++r) {
    const int crow = (r & 3) + 8 * (r >> 2) + 4 * hi;
    const int c0 = crow, c1 = 32 + crow;
    const int s0i = ((c0 >> 3) ^ (lo & 7)) << 3, s1i = ((c1 >> 3) ^ (lo & 7)) << 3;
    Ow[lo * 64 + s0i + (c0 & 7)] = f2b(o0[r] * inv0);
    Ow[lo * 64 + s1i + (c1 & 7)] = f2b(o1[r] * inv0);
    Ow[(32 + lo) * 64 + s0i + (c0 & 7)] = f2b(o2[r] * inv1);   // (32+lo)&7 == lo&7
    Ow[(32 + lo) * 64 + s1i + (c1 & 7)] = f2b(o3[r] * inv1);
  }
  if (hi == 0) {
    lbuf[((size_t)z * NHEAD + h) * N_TOK + q0w + lo] = lsum0;
    lbuf[((size_t)z * NHEAD + h) * N_TOK + q0w + 32 + lo] = lsum1;
  }
  asm volatile("s_waitcnt lgkmcnt(0)" ::: "memory");
  __builtin_amdgcn_sched_barrier(0);
  u16* pobase = PO + (((size_t)z * NHEAD + h) * N_TOK + q0w) * DHEAD;
#pragma unroll
  for (int i = 0; i < 8; ++i) {
    const int c = i * 64 + l;
    const int rr = c >> 3, sl = c & 7;
    bf16x8 v = *(const bf16x8*)(Ow + rr * 64 + sl * 8);
    const int cs = sl ^ (rr & 7);
    *(bf16x8*)(pobase + (size_t)rr * DHEAD + cs * 8) = v;
  }
}

// ---------- combine 4 partials: same base everywhere -> weights are just l_z ----------
__global__ __launch_bounds__(256)
void combine(const u16* __restrict__ PO, const float* __restrict__ lbuf,
             u16* __restrict__ attb) {
  const int idx = blockIdx.x * 256 + threadIdx.x;        // 0 .. 256*1024-1
  const int row = idx >> 3;                              // 0 .. N_TOK*NHEAD-1
  const int c8  = (idx & 7) * 8;
  const int h = row >> 11;
  const int q = row & (N_TOK - 1);

  float wsum = 0.f, acc8[8] = {};
#pragma unroll
  for (int zz = 0; zz < NSPLIT; ++zz) {
    const float wz = lbuf[((size_t)zz * NHEAD + h) * N_TOK + q];
    wsum += wz;
    bf16x8 po = *(const bf16x8*)(PO + (((size_t)zz * NHEAD + h) * N_TOK + q) * DHEAD + c8);
#pragma unroll
    for (int j = 0; j < 8; ++j) acc8[j] += wz * b2f((u16)po[j]);
  }
  const float invw = 1.0f / wsum;
  union { u16 s[8]; bf16x8 h8; } ov;
#pragma unroll
  for (int j = 0; j < 8; ++j) ov.s[j] = f2b(acc8[j] * invw);
  *(bf16x8*)(attb + (size_t)q * DMODEL + h * 64 + c8) = ov.h8;
}

// ---------- launch ----------
extern "C" void kernel_launch(void* const* d_in, const int* in_sizes, int n_in,
                              void* d_out, int out_size, void* d_ws, size_t ws_size,
                              hipStream_t stream) {
  const float* x      = (const float*)d_in[0];
  const float* w_qkv  = (const float*)d_in[1];
  const float* b_qkv  = (const float*)d_in[2];
  const float* w_proj = (const float*)d_in[3];
  const float* b_proj = (const float*)d_in[4];
  float* out = (float*)d_out;

  char* ws = (char*)d_ws;                          // flat layout, no aliasing
  u16*    xb     = (u16*)(ws + (0u  << 20));       //  4 MB
  u16*    wqkvb  = (u16*)(ws + (8u  << 20));       //  6 MB
  u16*    wprojb = (u16*)(ws + (16u << 20));       //  2 MB
  u16*    qkb    = (u16*)(ws + (24u << 20));       //  8 MB  (N x 2D: Q-scaled | K)
  u16*    vtg    = (u16*)(ws + (40u << 20));       //  4 MB  (H,DH,N)
  u16*    PO     = (u16*)(ws + (48u << 20));       // 16 MB  (4 splits)
  float*  lbuf   = (float*)(ws + (64u << 20));     //  0.5 MB
  u16*    attb   = (u16*)(ws + (66u << 20));       //  4 MB
  if (ws_size < (80u << 20)) return;

  cvt_all<<<6144, 256, 0, stream>>>(x, w_qkv, w_proj, xb, wqkvb, wprojb);

  // QKV GEMM, BM=128/BN=96 (MI=4,NI=3): 512 blocks = 2/CU, LDS-both (known-good).
  gemm_nt<false, true, 4, 3><<<dim3(QKV_N / 96, N_TOK / 128), 256, 0, stream>>>(
      xb, wqkvb, b_qkv, (void*)qkb, vtg, QK_LD, DMODEL);

  // 64 q/wave: 8 qb x 16 h x 4 z = 512 blocks = 2/CU, K/V frags reused across 2 q-groups
  attn3<<<8 * NHEAD * NSPLIT, 256, 0, stream>>>(qkb, vtg, PO, lbuf);

  combine<<<(N_TOK * NHEAD * 8) / 256, 256, 0, stream>>>(PO, lbuf, attb);

  // proj GEMM, BM=64/BN=64 (MI=2,NI=2): 512 blocks = 2/CU, LDS-both (R0/R4 config).
  gemm_nt<true, false, 2, 2><<<dim3(DMODEL / 64, N_TOK / 64), 256, 0, stream>>>(
      attb, wprojb, b_proj, (void*)out, nullptr, DMODEL, DMODEL);
}